// Round 1
// baseline (19048.122 us; speedup 1.0000x reference)
//
#include <hip/hip_runtime.h>
#include <hip/hip_bf16.h>
#include <stdint.h>

// GRU: B=256, S=512, E=256, H=512, C=128
// 8 teams x 32 WGs(CUs); team tm = wg&7, member cu = wg>>3.
// Team handles batch rows [32*tm, 32*tm+32); member owns h dims [16*cu, 16*cu+16)
// (gate rows {d, 512+d, 1024+d}).
// Per WG: 256 threads = 4 waves; wave w covers K range [192*w, 192*w+192) of the
// fused K=768 ( [x_t | h] @ [W_ih | W_hh]^T ), W slice held in VGPRs as bf16 frags.

typedef __attribute__((ext_vector_type(8))) short bf16x8;
typedef __attribute__((ext_vector_type(4))) short bf16x4;
typedef __attribute__((ext_vector_type(4))) float f32x4;

#define SWZ(r) (((r) & 7) << 4)

__device__ __forceinline__ unsigned short f2bf(float f) {
  unsigned x = __builtin_bit_cast(unsigned, f);
  unsigned r = (x + 0x7fffu + ((x >> 16) & 1u)) >> 16;  // RNE
  return (unsigned short)r;
}
__device__ __forceinline__ float bf2f(unsigned short u) {
  return __builtin_bit_cast(float, ((unsigned)u) << 16);
}

typedef const __attribute__((address_space(1))) unsigned int* gas_ptr;
typedef __attribute__((address_space(3))) unsigned int* las_ptr;
__device__ __forceinline__ void gload_lds16(const void* g, void* l) {
  // per-lane global src, wave-uniform LDS base (+lane*16 implicit)
  __builtin_amdgcn_global_load_lds((gas_ptr)g, (las_ptr)l, 16, 0, 0);
}

// cross-wave partial-sum buffer, aliased into the (dead-at-that-point) x region
// of in_vec: logical float index q -> LDS byte (q*4 laid into 512B chunks of
// each 1536B row).
__device__ __forceinline__ float& cbf(char* lds, int w, int ty, int r, int c) {
  int off = (((((w << 2) + ty) << 8) + (r << 4) + c) << 2);
  return *(float*)(lds + (off >> 9) * 1536 + (off & 511));
}

__global__ __launch_bounds__(256, 1) void gru_persistent(
    const float* __restrict__ x, const float* __restrict__ h0,
    const float* __restrict__ Wih, const float* __restrict__ Whh,
    const float* __restrict__ bih, const float* __restrict__ bhh,
    unsigned* __restrict__ ctr, unsigned short* __restrict__ hbuf) {
  // in_vec: 32 rows x 1536 B. bytes [0,512) = x_t (256 bf16), [512,1536) = h (512 bf16).
  // All LDS accesses use byte ^ SWZ(row) swizzle.
  __shared__ __align__(16) char lds[32 * 1536];

  const int tid = threadIdx.x;
  const int wg = blockIdx.x;
  const int tm = wg & 7;
  const int cu = wg >> 3;
  const int wv = tid >> 6;
  const int ln = tid & 63;
  const int bm = tm << 5;   // batch base
  const int d0 = cu << 4;   // h-dim slice base

  unsigned* tctr = ctr + tm * 32;
  char* hb0 = (char*)hbuf + (size_t)tm * 32768;
  char* hb1 = (char*)hbuf + (size_t)(8 + tm) * 32768;

  // ---- W slice -> registers (bf16 B-frags), loaded once ----
  bf16x8 BF[3][6];
  {
    const int j = ln & 15;
    const int kg = ln >> 4;
#pragma unroll
    for (int nf = 0; nf < 3; ++nf) {
      const int R = nf * 512 + d0 + j;
#pragma unroll
      for (int ks = 0; ks < 6; ++ks) {
        const int k = 192 * wv + 32 * ks + kg * 8;
        const float* src = (k < 256) ? (Wih + (size_t)R * 256 + k)
                                     : (Whh + (size_t)R * 512 + (k - 256));
        bf16x8 v;
#pragma unroll
        for (int i = 0; i < 8; ++i) v[i] = (short)f2bf(src[i]);
        BF[nf][ks] = v;
      }
    }
  }

  // ---- combine-thread constants: (rr = tid>>4 -> m within frag, dl = tid&15 -> dim) ----
  const int dl = tid & 15;
  const int rr = tid >> 4;
  const int dd = d0 + dl;
  const float bRv = bih[dd] + bhh[dd];
  const float bZv = bih[512 + dd] + bhh[512 + dd];
  const float bNxv = bih[1024 + dd];
  const float bNhv = bhh[1024 + dd];

  // fp32 hidden state carried in registers (2 rows per thread: m = rr, 16+rr)
  float hreg0 = h0[(size_t)(bm + rr) * 512 + dd];
  float hreg1 = h0[(size_t)(bm + 16 + rr) * 512 + dd];

  // ---- init h(0) into hb0 (own slice, bf16, swizzled) ----
  {
    const int m = tid & 31, q = tid >> 5;
    const int d = d0 + 2 * q;
    const size_t src = (size_t)(bm + m) * 512 + d;
    unsigned v = (unsigned)f2bf(h0[src]) | ((unsigned)f2bf(h0[src + 1]) << 16);
    *(unsigned*)(hb0 + m * 1024 + ((2 * d) ^ SWZ(m))) = v;
  }
  __threadfence();
  __syncthreads();
  if (tid == 0) __hip_atomic_fetch_add(tctr, 1u, __ATOMIC_RELAXED, __HIP_MEMORY_SCOPE_AGENT);

  // ---- x(0) prefetch (thread: row = tid>>3, i = tid&7; float4 e-index i + 8*j) ----
  const int xr_r = tid >> 3, xr_i = tid & 7;
  f32x4 xr[8];
  {
    const f32x4* xs = (const f32x4*)(x + ((size_t)(bm + xr_r) * 512 + 0) * 256) + xr_i;
#pragma unroll
    for (int jj = 0; jj < 8; ++jj) xr[jj] = xs[jj * 8];
  }

  for (int t = 0; t < 512; ++t) {
    // wait for h(t) from whole team
    if (tid == 0) {
      const unsigned tgt = 32u * (unsigned)(t + 1);
      while (__hip_atomic_load(tctr, __ATOMIC_RELAXED, __HIP_MEMORY_SCOPE_AGENT) < tgt)
        __builtin_amdgcn_s_sleep(1);
    }
    __syncthreads();
    __threadfence();  // acquire: invalidate stale cached h_buf

    // h(t) -> LDS (global already stored pre-swizzled; linear copy lands swizzled)
    {
      const char* hs = (t & 1) ? hb1 : hb0;
#pragma unroll
      for (int q = 0; q < 8; ++q) {
        const int r = wv * 8 + q;
        gload_lds16(hs + r * 1024 + ln * 16, lds + r * 1536 + 512);
      }
    }
    // x(t) regs -> LDS bf16 (swizzled)
    {
      char* rowb = lds + xr_r * 1536;
#pragma unroll
      for (int jj = 0; jj < 8; ++jj) {
        bf16x4 v;
        v[0] = (short)f2bf(xr[jj][0]);
        v[1] = (short)f2bf(xr[jj][1]);
        v[2] = (short)f2bf(xr[jj][2]);
        v[3] = (short)f2bf(xr[jj][3]);
        *(bf16x4*)(rowb + ((8 * xr_i + 64 * jj) ^ SWZ(xr_r))) = v;
      }
    }
    __syncthreads();  // drains vmcnt (gload_lds) + lgkm (ds_writes)

    // prefetch x(t+1) into regs (overlaps MFMA)
    if (t + 1 < 512) {
      const f32x4* xs =
          (const f32x4*)(x + ((size_t)(bm + xr_r) * 512 + (t + 1)) * 256) + xr_i;
#pragma unroll
      for (int jj = 0; jj < 8; ++jj) xr[jj] = xs[jj * 8];
    }

    // ---- MFMA: gates partials over this wave's K range ----
    f32x4 aR[2] = {}, aZ[2] = {}, aNx[2] = {}, aNh[2] = {};
    {
      const int arow = ln & 15;
      const int kg = ln >> 4;
#pragma unroll
      for (int ks = 0; ks < 6; ++ks) {
        const int p = 384 * wv + 64 * ks + 16 * kg;  // byte-in-row of A frag
        const bool isx = (192 * wv + 32 * ks) < 256; // fully x or fully h (wave-uniform)
#pragma unroll
        for (int mf = 0; mf < 2; ++mf) {
          const int row = arow + 16 * mf;
          bf16x8 a = *(const bf16x8*)(lds + row * 1536 + (p ^ SWZ(row)));
          aR[mf] = __builtin_amdgcn_mfma_f32_16x16x32_bf16(a, BF[0][ks], aR[mf], 0, 0, 0);
          aZ[mf] = __builtin_amdgcn_mfma_f32_16x16x32_bf16(a, BF[1][ks], aZ[mf], 0, 0, 0);
          if (isx)
            aNx[mf] = __builtin_amdgcn_mfma_f32_16x16x32_bf16(a, BF[2][ks], aNx[mf], 0, 0, 0);
          else
            aNh[mf] = __builtin_amdgcn_mfma_f32_16x16x32_bf16(a, BF[2][ks], aNh[mf], 0, 0, 0);
        }
      }
    }

    // ---- cross-wave combine (2 passes over m-frags; cbuf aliases dead x region) ----
    char* hdst = ((t + 1) & 1) ? hb1 : hb0;
#pragma unroll
    for (int mf = 0; mf < 2; ++mf) {
      __syncthreads();  // x region dead / previous pass reads done
      {
        const int cr0 = (ln >> 4) * 2;  // C rows 4*(ln>>4)+i ; write 4 regs
        const int cc = ln & 15;
#pragma unroll
        for (int i = 0; i < 4; ++i) {
          const int crow = (ln >> 4) * 4 + i;
          cbf(lds, wv, 0, crow, cc) = aR[mf][i];
          cbf(lds, wv, 1, crow, cc) = aZ[mf][i];
          if (wv <= 1) cbf(lds, wv, 2, crow, cc) = aNx[mf][i];
          if (wv >= 1) cbf(lds, wv, 3, crow, cc) = aNh[mf][i];
        }
        (void)cr0;
      }
      __syncthreads();
      {
        const int m = mf * 16 + rr;
        float rpre = bRv + cbf(lds, 0, 0, rr, dl) + cbf(lds, 1, 0, rr, dl) +
                     cbf(lds, 2, 0, rr, dl) + cbf(lds, 3, 0, rr, dl);
        float zpre = bZv + cbf(lds, 0, 1, rr, dl) + cbf(lds, 1, 1, rr, dl) +
                     cbf(lds, 2, 1, rr, dl) + cbf(lds, 3, 1, rr, dl);
        float inx = bNxv + cbf(lds, 0, 2, rr, dl) + cbf(lds, 1, 2, rr, dl);
        float hnn = bNhv + cbf(lds, 1, 3, rr, dl) + cbf(lds, 2, 3, rr, dl) +
                    cbf(lds, 3, 3, rr, dl);
        const float rg = 1.f / (1.f + __expf(-rpre));
        const float zg = 1.f / (1.f + __expf(-zpre));
        const float npre = inx + rg * hnn;
        const float e2 = __expf(2.f * npre);
        const float ng = 1.f - 2.f / (e2 + 1.f);  // tanh, overflow-stable
        const float hold = (mf == 0) ? hreg0 : hreg1;
        const float hnew = ng + zg * (hold - ng);  // (1-z)n + z*h
        if (mf == 0) hreg0 = hnew; else hreg1 = hnew;
        *(unsigned short*)(hdst + m * 1024 + ((2 * dd) ^ SWZ(m))) = f2bf(hnew);
      }
    }

    __threadfence();  // release h(t+1) stores
    __syncthreads();
    if (tid == 0)
      __hip_atomic_fetch_add(tctr, 1u, __ATOMIC_RELAXED, __HIP_MEMORY_SCOPE_AGENT);
  }
}

// ---- logits + masked CE + accuracy partials; one WG per batch row ----
__global__ __launch_bounds__(128) void logits_loss(
    const unsigned short* __restrict__ hbuf, const float* __restrict__ Wout,
    const float* __restrict__ bout, const int* __restrict__ label,
    float* __restrict__ accv) {
  __shared__ float hrow[512];
  __shared__ float lg[128];
  const int b = blockIdx.x;
  const int tm = b >> 5, r = b & 31;
  const char* base = (const char*)hbuf + (size_t)tm * 32768 + r * 1024;
  for (int i = threadIdx.x; i < 256; i += 128) {
    unsigned v = *(const unsigned*)(base + ((i * 4) ^ SWZ(r)));
    hrow[2 * i] = bf2f((unsigned short)(v & 0xffff));
    hrow[2 * i + 1] = bf2f((unsigned short)(v >> 16));
  }
  __syncthreads();
  const int c = threadIdx.x;
  const f32x4* w4 = (const f32x4*)(Wout + (size_t)c * 512);
  const f32x4* h4 = (const f32x4*)hrow;
  float s = bout[c];
#pragma unroll 4
  for (int i = 0; i < 128; ++i) {
    f32x4 wv = w4[i], hv = h4[i];
    s += wv[0] * hv[0] + wv[1] * hv[1] + wv[2] * hv[2] + wv[3] * hv[3];
  }
  lg[c] = s;
  __syncthreads();
  if (c == 0) {
    float mx = lg[0];
    int am = 0;
    for (int i = 1; i < 128; ++i)
      if (lg[i] > mx) { mx = lg[i]; am = i; }  // first-max tiebreak like argmax
    float se = 0.f;
    for (int i = 0; i < 128; ++i) se += __expf(lg[i] - mx);
    const int lb = label[b];
    const float logp = lg[lb] - mx - __logf(se);
    if (lb != 0) {
      atomicAdd(&accv[0], -logp);
      atomicAdd(&accv[1], 1.0f);
    }
    if (am == lb) atomicAdd(&accv[2], 1.0f);
  }
}

__global__ void finalize_k(const float* __restrict__ accv, float* __restrict__ out) {
  out[0] = accv[0] / fmaxf(accv[1], 1.0f);
  out[1] = accv[2] * (1.0f / 256.0f);
}

extern "C" void kernel_launch(void* const* d_in, const int* in_sizes, int n_in,
                              void* d_out, int out_size, void* d_ws, size_t ws_size,
                              hipStream_t stream) {
  (void)in_sizes; (void)n_in; (void)out_size; (void)ws_size;
  const float* x = (const float*)d_in[0];
  const int* label = (const int*)d_in[1];
  const float* h0 = (const float*)d_in[2];
  const float* Wih = (const float*)d_in[3];
  const float* Whh = (const float*)d_in[4];
  const float* bih = (const float*)d_in[5];
  const float* bhh = (const float*)d_in[6];
  const float* Wout = (const float*)d_in[7];
  const float* bout = (const float*)d_in[8];
  float* out = (float*)d_out;

  char* ws = (char*)d_ws;
  unsigned* ctr = (unsigned*)ws;                    // 8 teams * 32 u32 (128B apart)
  float* accv = (float*)(ws + 2048);                // 3 accumulators
  unsigned short* hbuf = (unsigned short*)(ws + 4096);  // 2 x 8 x 32KB double buffer

  // deterministic re-init each call (graph-replay safe)
  hipMemsetAsync(ws, 0, 4096, stream);

  gru_persistent<<<dim3(256), dim3(256), 0, stream>>>(x, h0, Wih, Whh, bih, bhh,
                                                      ctr, hbuf);
  logits_loss<<<dim3(256), dim3(128), 0, stream>>>(hbuf, Wout, bout, label, accv);
  finalize_k<<<dim3(1), dim3(1), 0, stream>>>(accv, out);
}

// Round 2
// 1546.047 us; speedup vs baseline: 12.3205x; 12.3205x over previous
//
#include <hip/hip_runtime.h>
#include <hip/hip_bf16.h>
#include <stdint.h>

// GRU: B=256, S=512, E=256, H=512, C=128
// 16 teams x 16 WGs. team tm = wg&15 (members wg ≡ tm mod 16 -> same XCD under
// round-robin, perf only); member cu = wg>>4 owns h dims [32*cu, 32*cu+32).
// Team handles batch rows [16*tm, 16*tm+16)  (M=16 -> single MFMA m-frag).
// Per WG: 256 threads = 4 waves; wave w covers K range [192*w, 192*w+192) of
// fused K=768 ([x_t | h] @ [W_ih | W_hh]^T); W slice lives in VGPRs (144/lane).
// h exchange: per-access system-scope (sc0 sc1) stores/loads through MALL —
// coherent across XCDs with NO cache-wide fences. Sync: per-WG seq flags
// (flag=v  <=>  this WG wrote h(v-1)), polled with sc1 loads.

typedef __attribute__((ext_vector_type(8))) short bf16x8;
typedef __attribute__((ext_vector_type(4))) float f32x4;

#define SWZ(r) (((r)&7) << 4)

static __device__ __forceinline__ unsigned short f2bf(float f) {
  unsigned x = __builtin_bit_cast(unsigned, f);
  unsigned r = (x + 0x7fffu + ((x >> 16) & 1u)) >> 16;  // RNE
  return (unsigned short)r;
}
static __device__ __forceinline__ float bf2f(unsigned u) {
  return __builtin_bit_cast(float, u << 16);
}

static __device__ __forceinline__ void st_sys_u32(void* p, unsigned v) {
  asm volatile("global_store_dword %0, %1, off sc0 sc1" :: "v"(p), "v"(v) : "memory");
}

__global__ __launch_bounds__(256, 1) void gru_persistent(
    const float* __restrict__ x, const float* __restrict__ h0,
    const float* __restrict__ Wih, const float* __restrict__ Whh,
    const float* __restrict__ bih, const float* __restrict__ bhh,
    unsigned* __restrict__ flags, unsigned short* __restrict__ hbuf) {
  // in_vec: 16 rows x 1536 B: [0,512) = x_t (256 bf16), [512,1536) = h (512 bf16).
  // byte-in-row swizzled with ^SWZ(row).
  __shared__ __align__(16) char ldsb[16 * 1536];
  __shared__ __align__(16) float cb[4 * 4 * 2 * 256];  // [wave][type][nf][row*16+col]

  const int tid = threadIdx.x, wg = blockIdx.x;
  const int tm = wg & 15, cu = wg >> 4;
  const int wv = tid >> 6, ln = tid & 63;
  const int bm = tm << 4;   // batch base
  const int d0 = cu << 5;   // h-dim slice base (32 dims)

  unsigned* tfl = flags + tm * 32;  // 16 flags used, teams 128 B apart
  char* hs0 = (char*)hbuf + (size_t)tm * 16384;
  char* hs1 = (char*)hbuf + 262144 + (size_t)tm * 16384;

  // ---- W slice -> VGPR bf16 B-frags (once) ----
  bf16x8 BF[3][2][6];
  {
    const int j = ln & 15, kg = ln >> 4;
#pragma unroll
    for (int g = 0; g < 3; ++g)
#pragma unroll
      for (int nf = 0; nf < 2; ++nf)
#pragma unroll
        for (int ks = 0; ks < 6; ++ks) {
          const int R = g * 512 + d0 + nf * 16 + j;
          const int k = 192 * wv + 32 * ks + 8 * kg;
          const float* src = (k < 256) ? Wih + (size_t)R * 256 + k
                                       : Whh + (size_t)R * 512 + (k - 256);
          bf16x8 v;
#pragma unroll
          for (int i = 0; i < 8; ++i) v[i] = (short)f2bf(src[i]);
          BF[g][nf][ks] = v;
        }
  }

  // ---- per-thread combine constants: row rr, dims dd0 (nf0) / dd1 (nf1) ----
  const int dl = tid & 15, rr = tid >> 4;
  const int dd0 = d0 + dl, dd1 = d0 + 16 + dl;
  const float bR0 = bih[dd0] + bhh[dd0], bR1 = bih[dd1] + bhh[dd1];
  const float bZ0 = bih[512 + dd0] + bhh[512 + dd0], bZ1 = bih[512 + dd1] + bhh[512 + dd1];
  const float bNx0 = bih[1024 + dd0], bNx1 = bih[1024 + dd1];
  const float bNh0 = bhh[1024 + dd0], bNh1 = bhh[1024 + dd1];

  float hr0 = h0[(size_t)(bm + rr) * 512 + dd0];
  float hr1 = h0[(size_t)(bm + rr) * 512 + dd1];

  // ---- h(0) -> hbuf slot 0 (pre-swizzled, pair-packed, system-scope) ----
  {
    unsigned a0 = f2bf(hr0), a1 = f2bf(hr1);
    unsigned p0 = __shfl_xor(a0, 1, 64), p1 = __shfl_xor(a1, 1, 64);
    if (!(dl & 1)) {
      st_sys_u32(hs0 + rr * 1024 + ((2 * dd0) ^ SWZ(rr)), a0 | (p0 << 16));
      st_sys_u32(hs0 + rr * 1024 + ((2 * dd1) ^ SWZ(rr)), a1 | (p1 << 16));
    }
  }
  asm volatile("s_waitcnt vmcnt(0)" ::: "memory");
  __syncthreads();
  if (tid == 0) st_sys_u32(tfl + cu, 1u);

  // ---- x(0) prefetch: thread covers row tid>>4, floats [16*(tid&15), +16) ----
  const int xr = tid >> 4, xi = tid & 15;
  f32x4 xv[4];
  {
    const float* xb = x + ((size_t)(bm + xr) * 512 + 0) * 256 + xi * 16;
#pragma unroll
    for (int q = 0; q < 4; ++q) xv[q] = *(const f32x4*)(xb + 4 * q);
  }

  for (int t = 0; t < 512; ++t) {
    // ---- wait for h(t): all 16 team flags >= t+1 ----
    if (wv == 0) {
      const unsigned* fp = tfl + (ln & 15);
      const unsigned tgt = (unsigned)(t + 1);
      while (true) {
        unsigned fv;
        asm volatile("global_load_dword %0, %1, off sc0 sc1\n\ts_waitcnt vmcnt(0)"
                     : "=v"(fv) : "v"(fp) : "memory");
        if (__ballot(fv >= tgt) == ~0ull) break;
      }
    }
    __syncthreads();  // A

    // ---- issue h(t) system-scope loads (16 KB/WG), then stage x(t) under them ----
    const char* hsrc = (t & 1) ? hs1 : hs0;
    f32x4 t0, t1, t2, t3;
    asm volatile("global_load_dwordx4 %0, %1, off sc0 sc1"
                 : "=v"(t0) : "v"(hsrc + (wv * 4 + 0) * 1024 + ln * 16) : "memory");
    asm volatile("global_load_dwordx4 %0, %1, off sc0 sc1"
                 : "=v"(t1) : "v"(hsrc + (wv * 4 + 1) * 1024 + ln * 16) : "memory");
    asm volatile("global_load_dwordx4 %0, %1, off sc0 sc1"
                 : "=v"(t2) : "v"(hsrc + (wv * 4 + 2) * 1024 + ln * 16) : "memory");
    asm volatile("global_load_dwordx4 %0, %1, off sc0 sc1"
                 : "=v"(t3) : "v"(hsrc + (wv * 4 + 3) * 1024 + ln * 16) : "memory");
    {
      char* rowb = ldsb + xr * 1536;
      bf16x8 xa, xb;
#pragma unroll
      for (int q = 0; q < 4; ++q) {
        xa[q] = (short)f2bf(xv[0][q]); xa[4 + q] = (short)f2bf(xv[1][q]);
        xb[q] = (short)f2bf(xv[2][q]); xb[4 + q] = (short)f2bf(xv[3][q]);
      }
      *(bf16x8*)(rowb + ((32 * xi) ^ SWZ(xr))) = xa;
      *(bf16x8*)(rowb + ((32 * xi + 16) ^ SWZ(xr))) = xb;
    }
    asm volatile("s_waitcnt vmcnt(0)" : "+v"(t0), "+v"(t1), "+v"(t2), "+v"(t3) :: "memory");
    *(f32x4*)(ldsb + (wv * 4 + 0) * 1536 + 512 + ln * 16) = t0;
    *(f32x4*)(ldsb + (wv * 4 + 1) * 1536 + 512 + ln * 16) = t1;
    *(f32x4*)(ldsb + (wv * 4 + 2) * 1536 + 512 + ln * 16) = t2;
    *(f32x4*)(ldsb + (wv * 4 + 3) * 1536 + 512 + ln * 16) = t3;
    __syncthreads();  // B

    // ---- x(t+1) reg prefetch (plain loads, overlap MFMA) ----
    if (t + 1 < 512) {
      const float* xb2 = x + ((size_t)(bm + xr) * 512 + (t + 1)) * 256 + xi * 16;
#pragma unroll
      for (int q = 0; q < 4; ++q) xv[q] = *(const f32x4*)(xb2 + 4 * q);
    }

    // ---- MFMA: this wave's K range, 32 dims (2 nf) x 3 gates ----
    f32x4 aR[2] = {}, aZ[2] = {}, aNx[2] = {}, aNh[2] = {};
    {
      const int arow = ln & 15, kg = ln >> 4;
#pragma unroll
      for (int ks = 0; ks < 6; ++ks) {
        const int p = 384 * wv + 64 * ks + 16 * kg;
        bf16x8 a = *(const bf16x8*)(ldsb + arow * 1536 + (p ^ SWZ(arow)));
        const bool isx = (192 * wv + 32 * ks) < 256;
#pragma unroll
        for (int nf = 0; nf < 2; ++nf) {
          aR[nf] = __builtin_amdgcn_mfma_f32_16x16x32_bf16(a, BF[0][nf][ks], aR[nf], 0, 0, 0);
          aZ[nf] = __builtin_amdgcn_mfma_f32_16x16x32_bf16(a, BF[1][nf][ks], aZ[nf], 0, 0, 0);
          if (isx)
            aNx[nf] = __builtin_amdgcn_mfma_f32_16x16x32_bf16(a, BF[2][nf][ks], aNx[nf], 0, 0, 0);
          else
            aNh[nf] = __builtin_amdgcn_mfma_f32_16x16x32_bf16(a, BF[2][nf][ks], aNh[nf], 0, 0, 0);
        }
      }
    }

    // ---- cross-wave partials -> cbuf ----
    {
      const int cc = ln & 15, cg = ln >> 4;
#pragma unroll
      for (int nf = 0; nf < 2; ++nf)
#pragma unroll
        for (int i = 0; i < 4; ++i) {
          const int row = cg * 4 + i;
          cb[((wv * 4 + 0) * 2 + nf) * 256 + row * 16 + cc] = aR[nf][i];
          cb[((wv * 4 + 1) * 2 + nf) * 256 + row * 16 + cc] = aZ[nf][i];
          if (wv <= 1) cb[((wv * 4 + 2) * 2 + nf) * 256 + row * 16 + cc] = aNx[nf][i];
          if (wv >= 1) cb[((wv * 4 + 3) * 2 + nf) * 256 + row * 16 + cc] = aNh[nf][i];
        }
    }
    __syncthreads();  // D

    // ---- combine + gate math (fp32), h kept in regs ----
    char* hdst = ((t + 1) & 1) ? hs1 : hs0;
    {
#define CB(w, ty, nf) cb[(((w) * 4 + (ty)) * 2 + (nf)) * 256 + rr * 16 + dl]
      float rp0 = bR0 + CB(0,0,0) + CB(1,0,0) + CB(2,0,0) + CB(3,0,0);
      float rp1 = bR1 + CB(0,0,1) + CB(1,0,1) + CB(2,0,1) + CB(3,0,1);
      float zp0 = bZ0 + CB(0,1,0) + CB(1,1,0) + CB(2,1,0) + CB(3,1,0);
      float zp1 = bZ1 + CB(0,1,1) + CB(1,1,1) + CB(2,1,1) + CB(3,1,1);
      float ix0 = bNx0 + CB(0,2,0) + CB(1,2,0);
      float ix1 = bNx1 + CB(0,2,1) + CB(1,2,1);
      float hn0 = bNh0 + CB(1,3,0) + CB(2,3,0) + CB(3,3,0);
      float hn1 = bNh1 + CB(1,3,1) + CB(2,3,1) + CB(3,3,1);
#undef CB
      const float rg0 = 1.f / (1.f + __expf(-rp0)), rg1 = 1.f / (1.f + __expf(-rp1));
      const float zg0 = 1.f / (1.f + __expf(-zp0)), zg1 = 1.f / (1.f + __expf(-zp1));
      const float e0 = __expf(2.f * (ix0 + rg0 * hn0));
      const float e1 = __expf(2.f * (ix1 + rg1 * hn1));
      const float ng0 = 1.f - 2.f / (e0 + 1.f), ng1 = 1.f - 2.f / (e1 + 1.f);
      hr0 = ng0 + zg0 * (hr0 - ng0);
      hr1 = ng1 + zg1 * (hr1 - ng1);
    }

    // ---- h(t+1) -> hbuf (pair-packed u32, system-scope) ----
    {
      unsigned a0 = f2bf(hr0), a1 = f2bf(hr1);
      unsigned p0 = __shfl_xor(a0, 1, 64), p1 = __shfl_xor(a1, 1, 64);
      if (!(dl & 1)) {
        st_sys_u32(hdst + rr * 1024 + ((2 * dd0) ^ SWZ(rr)), a0 | (p0 << 16));
        st_sys_u32(hdst + rr * 1024 + ((2 * dd1) ^ SWZ(rr)), a1 | (p1 << 16));
      }
    }
    asm volatile("s_waitcnt vmcnt(0)" ::: "memory");  // h stores acked at MALL
    __syncthreads();  // E
    if (tid == 0) st_sys_u32(tfl + cu, (unsigned)(t + 2));
  }
}

// ---- logits + masked CE + accuracy; one WG per batch row ----
__global__ __launch_bounds__(128) void logits_loss(
    const unsigned short* __restrict__ hbuf, const float* __restrict__ Wout,
    const float* __restrict__ bout, const int* __restrict__ label,
    float* __restrict__ accv) {
  __shared__ float hrow[512];
  __shared__ float lg[128];
  const int b = blockIdx.x;
  const int tm = b >> 4, r = b & 15;
  const char* base = (const char*)hbuf + (size_t)tm * 16384 + r * 1024;
  for (int i = threadIdx.x; i < 256; i += 128) {
    const char* p = base + ((i * 4) ^ SWZ(r));
    unsigned v;
    asm volatile("global_load_dword %0, %1, off sc0 sc1\n\ts_waitcnt vmcnt(0)"
                 : "=v"(v) : "v"(p) : "memory");
    hrow[2 * i] = bf2f(v & 0xffffu);
    hrow[2 * i + 1] = bf2f(v >> 16);
  }
  __syncthreads();
  const int c = threadIdx.x;
  const f32x4* w4 = (const f32x4*)(Wout + (size_t)c * 512);
  const f32x4* h4 = (const f32x4*)hrow;
  float s = bout[c];
#pragma unroll 4
  for (int i = 0; i < 128; ++i) {
    f32x4 wv = w4[i], hv = h4[i];
    s += wv[0] * hv[0] + wv[1] * hv[1] + wv[2] * hv[2] + wv[3] * hv[3];
  }
  lg[c] = s;
  __syncthreads();
  if (c == 0) {
    float mx = lg[0];
    int am = 0;
    for (int i = 1; i < 128; ++i)
      if (lg[i] > mx) { mx = lg[i]; am = i; }
    float se = 0.f;
    for (int i = 0; i < 128; ++i) se += __expf(lg[i] - mx);
    const int lb = label[b];
    const float logp = lg[lb] - mx - __logf(se);
    if (lb != 0) {
      atomicAdd(&accv[0], -logp);
      atomicAdd(&accv[1], 1.0f);
    }
    if (am == lb) atomicAdd(&accv[2], 1.0f);
  }
}

__global__ void finalize_k(const float* __restrict__ accv, float* __restrict__ out) {
  out[0] = accv[0] / fmaxf(accv[1], 1.0f);
  out[1] = accv[2] * (1.0f / 256.0f);
}

extern "C" void kernel_launch(void* const* d_in, const int* in_sizes, int n_in,
                              void* d_out, int out_size, void* d_ws, size_t ws_size,
                              hipStream_t stream) {
  (void)in_sizes; (void)n_in; (void)out_size; (void)ws_size;
  const float* x = (const float*)d_in[0];
  const int* label = (const int*)d_in[1];
  const float* h0 = (const float*)d_in[2];
  const float* Wih = (const float*)d_in[3];
  const float* Whh = (const float*)d_in[4];
  const float* bih = (const float*)d_in[5];
  const float* bhh = (const float*)d_in[6];
  const float* Wout = (const float*)d_in[7];
  const float* bout = (const float*)d_in[8];
  float* out = (float*)d_out;

  char* ws = (char*)d_ws;
  unsigned* flags = (unsigned*)ws;                      // 16 teams * 128 B
  float* accv = (float*)(ws + 4096);                    // 3 accumulators
  unsigned short* hbuf = (unsigned short*)(ws + 8192);  // 2 slots x 16 teams x 16 KB

  hipMemsetAsync(ws, 0, 8192, stream);  // flags + accv: deterministic per call

  gru_persistent<<<dim3(256), dim3(256), 0, stream>>>(x, h0, Wih, Whh, bih, bhh,
                                                      flags, hbuf);
  logits_loss<<<dim3(256), dim3(128), 0, stream>>>(hbuf, Wout, bout, label, accv);
  finalize_k<<<dim3(1), dim3(1), 0, stream>>>(accv, out);
}